// Round 9
// baseline (781.719 us; speedup 1.0000x reference)
//
#include <hip/hip_runtime.h>
#include <stdint.h>

typedef unsigned short u16;
typedef float f32x4 __attribute__((ext_vector_type(4)));
typedef int   i32x4 __attribute__((ext_vector_type(4)));

__device__ __forceinline__ u16 f2bf(float f){
  union { float f; uint32_t u; } v; v.f = f;
  uint32_t r = v.u + 0x7FFFu + ((v.u >> 16) & 1u);
  return (u16)(r >> 16);
}
__device__ __forceinline__ float bf2f(u16 b){
  union { uint32_t u; float f; } v; v.u = ((uint32_t)b) << 16; return v.f;
}
// fast sigmoid / tanh: v_exp + v_rcp (no full-precision div)
__device__ __forceinline__ float sigm(float x){
  return __builtin_amdgcn_rcpf(1.0f + __expf(-x));
}
__device__ __forceinline__ float tanhf_(float x){
  float t = __builtin_amdgcn_rcpf(__expf(2.0f*x) + 1.0f);
  return 1.0f - 2.0f*t;
}
__device__ __forceinline__ f32x4 mfma16(i32x4 a, i32x4 b, f32x4 c){
  asm("v_mfma_f32_16x16x32_bf16 %0, %1, %2, %0" : "+v"(c) : "v"(a), "v"(b));
  return c;
}
__device__ __forceinline__ void stage16(u16* lds_wave_base, const u16* g){
  uint32_t* l32 = (uint32_t*)lds_wave_base;
  __builtin_amdgcn_global_load_lds((const __attribute__((address_space(1))) uint32_t*)g,
                                   (__attribute__((address_space(3))) uint32_t*)l32,
                                   16, 0, 0);
}

// ---------------- small utility kernels ----------------

// wih f32 -> bf16 with gate-interleave permutation folded in:
// dst[d][p][k] = src[d][(p&3)*128 + (p>>2)][k]   (p in [0,512), k in [0,K))
__global__ void k_f2bf_perm(const float* __restrict__ src, u16* __restrict__ dst, int Klog){
  int i = blockIdx.x*256 + threadIdx.x;     // exactly 2*512*K threads launched
  int K = 1 << Klog;
  int k = i & (K-1);
  int p = (i >> Klog) & 511;
  int d = i >> (Klog + 9);
  int orig = ((p & 3) << 7) | (p >> 2);
  dst[i] = f2bf(src[(((size_t)d*512 + orig) << Klog) + k]);
}

__global__ void k_ctx(const float* __restrict__ ctx,
                      const float* __restrict__ fc1w, const float* __restrict__ fc1b,
                      const float* __restrict__ fcrw, const float* __restrict__ fcrb,
                      u16* __restrict__ c1b, u16* __restrict__ crb){
  int idx = blockIdx.x*256 + threadIdx.x;
  if (idx < 4096){
    int n = idx >> 9, j = idx & 511;
    const float* c = ctx + n*128; const float* w = fc1w + j*128;
    float s = fc1b[j];
    for (int k=0;k<128;k++) s += c[k]*w[k];
    c1b[idx] = f2bf(s);
  } else if (idx < 6144){
    int t = idx - 4096; int n = t >> 8, j = t & 255;
    const float* c = ctx + n*128; const float* w = fcrw + j*128;
    float s = fcrb[j];
    for (int k=0;k<128;k++) s += c[k]*w[k];
    crb[t] = f2bf(s);
  }
}

__global__ void k_ends(u16* __restrict__ seq, const u16* __restrict__ ctxb,
                       int S, int T, int D, int P1){
  int idx = blockIdx.x*256 + threadIdx.x;
  if (idx >= S*D) return;
  int s = idx / D, c = idx % D;
  int n = s / P1;
  u16 v = ctxb[n*D + c];
  size_t base = (size_t)s * T * D;
  seq[base + c] = v;
  seq[base + (size_t)(T-1)*D + c] = v;
}

__global__ void k_tr(const float* __restrict__ lf, u16* __restrict__ seq){
  __shared__ float tile[32][81];
  int s = blockIdx.x;            // n*60+h
  int n = s / 60;
  int h = s - n*60;
  int c0 = blockIdx.y * 32;
  const float* src = lf + ((size_t)(n*512 + c0)*60 + h)*80;
  for (int i = 0; i < 10; i++){
    int idx = i*256 + threadIdx.x;   // 2560 = 32c*80w
    int w = idx % 80, ci = idx / 80;
    tile[ci][w] = src[(size_t)ci*4800 + w];
  }
  __syncthreads();
  u16* dst = seq + (size_t)s*82*512 + c0;
  for (int i = 0; i < 10; i++){
    int idx = i*256 + threadIdx.x;
    int ci = idx % 32, w = idx / 32;
    dst[(size_t)(w+1)*512 + ci] = f2bf(tile[ci][w]);
  }
}

// ---------------- GEMM: gx[m][p] = seq[m][:] @ wperm[p][:] + bias[perm(p)] ----------------
// r9: double-buffered LDS (2x16KB), stage-early: issue next round's
// global_load_lds BEFORE current round's ds_read+MFMA, single barrier per
// round AFTER MFMA (T3 minimum-2-phase). MFMA order unchanged -> bit-identical.
// XCD-aware mapping kept: wgid = r + 8*j + 64*q, m = 8q+r.
__launch_bounds__(256)
__global__ void k_gemm(const u16* __restrict__ A, const u16* __restrict__ Bw,
                       const float* __restrict__ bih, const float* __restrict__ bhh,
                       u16* __restrict__ gx, int Mpad, int K, int Mb){
  const int wg = blockIdx.x;
  const int q = wg >> 6, rem = wg & 63;
  const int j = rem >> 3, r8 = rem & 7;
  const int m = q*8 + r8;
  if (m >= Mb) return;
  const int m0 = m * 128;
  const int n0 = (j & 3) * 128;
  const int d = j >> 2;

  __shared__ __align__(16) u16 As[2][4096];
  __shared__ __align__(16) u16 Bs[2][4096];
  const int tid = threadIdx.x;
  const u16* Bd = Bw + (size_t)d * 512 * K;
  const int lane = tid & 63, wid = tid >> 6;
  const int wy = wid >> 1, wx = wid & 1;
  const int l15 = lane & 15, g4 = lane >> 4;
  const int lr = lane & 15;     // staged row within 16-row region
  const int lg = lane >> 4;     // staged k-granule (8 u16 = 16B)

  f32x4 acc[4][4];
#pragma unroll
  for (int i=0;i<4;i++)
#pragma unroll
    for (int jj=0;jj<4;jj++) acc[i][jj] = 0.0f;

  const size_t arow_lo = (size_t)(m0 + wid*16      + lr)*K + lg*8;
  const size_t arow_hi = (size_t)(m0 + 64 + wid*16 + lr)*K + lg*8;
  const size_t brow_lo = (size_t)(n0 + wid*16      + lr)*K + lg*8;
  const size_t brow_hi = (size_t)(n0 + 64 + wid*16 + lr)*K + lg*8;

#define STAGE(B, K0) { \
    stage16(&As[B][wid*512],        A  + arow_lo + (K0)); \
    stage16(&As[B][wid*512 + 2048], A  + arow_hi + (K0)); \
    stage16(&Bs[B][wid*512],        Bd + brow_lo + (K0)); \
    stage16(&Bs[B][wid*512 + 2048], Bd + brow_hi + (K0)); \
  }

  STAGE(0, 0)
  __syncthreads();                 // drains vmcnt: buf0 ready

  int cur = 0;
  for (int k0 = 0; k0 < K; k0 += 32){
    const bool more = (k0 + 32 < K);
    if (more) STAGE(cur^1, k0+32)  // issue next-round staging early
    i32x4 af[4], bfr[4];
#pragma unroll
    for (int i=0;i<4;i++){
      af[i]  = *(const i32x4*)&As[cur][wy*2048 + i*512 + lane*8];
      bfr[i] = *(const i32x4*)&Bs[cur][wx*2048 + i*512 + lane*8];
    }
#pragma unroll
    for (int i=0;i<4;i++)
#pragma unroll
      for (int jj=0;jj<4;jj++)
        acc[i][jj] = mfma16(af[i], bfr[jj], acc[i][jj]);
    if (more){
      __syncthreads();             // drains staging; all waves done reading cur
      cur ^= 1;
    }
  }
#undef STAGE

  asm volatile("s_nop 7\ns_nop 7\ns_nop 7\ns_nop 7":::);
#pragma unroll
  for (int jj=0;jj<4;jj++){
    int col = n0 + wx*64 + jj*16 + l15;
    int orig = ((col & 3) << 7) | (col >> 2);
    float bs = bih[d*512 + orig] + bhh[d*512 + orig];
#pragma unroll
    for (int i=0;i<4;i++){
      int row = m0 + wy*64 + i*16 + g4*4;
      size_t base = ((size_t)d*Mpad + row)*512 + col;
#pragma unroll
      for (int r=0;r<4;r++)
        gx[base + (size_t)r*512] = f2bf(acc[i][jj][r] + bs);
    }
  }
}

// ---------------- LSTM scan: 1 WG = 8 sequences x 1 direction ----------------
// (unchanged r6 body — bit-exact; depth-2 named prefetch, lgkm-only barrier)
__launch_bounds__(512, 2)
__global__ void k_scan(const u16* __restrict__ gx, const float* __restrict__ whh,
                       u16* __restrict__ outp, int S, int T, int P1, int Mpad,
                       int SN, int SP, int SQ, int OFF){
  __shared__ __align__(16) u16 hbuf[2][8][128];
  const int tid = threadIdx.x;
  const int lane = tid & 63, w = tid >> 6;
  const int l15 = lane & 15, g4 = lane >> 4;
  const int d = blockIdx.y;
  const int s0 = blockIdx.x * 8;
  const int gcol = w*16 + l15;
  const int l7 = l15 & 7;
  const int sw_rd = l7 << 3;
  const int row4 = (g4 & 1) * 4;          // real output rows for g4<2; mirror for g4>=2
  const bool realln = (g4 < 2);

  for (int i = tid; i < 2*8*128; i += 512) ((u16*)hbuf)[i] = 0;

  // B fragments: whh[d][g*128+gcol][k], k = kk*32 + g4*8 + j (same bijection as A side)
  i32x4 bw[4][4];
  {
    const float* wb = whh + (size_t)d*512*128;
#pragma unroll
    for (int g=0; g<4; g++){
      const float* wr = wb + (size_t)(g*128 + gcol)*128 + g4*8;
#pragma unroll
      for (int kk=0; kk<4; kk++){
        f32x4 lo = *(const f32x4*)(wr + kk*32);
        f32x4 hi = *(const f32x4*)(wr + kk*32 + 4);
        union { u16 h[8]; i32x4 v; } u;
#pragma unroll
        for (int j=0;j<4;j++){ u.h[j] = f2bf(lo[j]); u.h[4+j] = f2bf(hi[j]); }
        bw[g][kk] = u.v;
      }
    }
  }

  size_t gbase[4]; size_t ob[4];
#pragma unroll
  for (int r=0;r<4;r++){
    int s = s0 + row4 + r;                 // g4>=2 duplicates g4-2's rows
    gbase[r] = ((size_t)d*Mpad + (size_t)s*T)*512 + gcol*4;
    int n = s / P1, p = s - n*P1;
    ob[r] = (size_t)n*SN + (size_t)p*SP + OFF + d*128 + gcol;
  }

  float c4[4] = {0.f,0.f,0.f,0.f};
  uint2 gva[4], gvb[4];
  {
    int t0 = d ? (T-1) : 0;
    int t1 = d ? (T-2) : 1;
#pragma unroll
    for (int r=0;r<4;r++){
      gva[r] = *(const uint2*)&gx[gbase[r] + (size_t)t0*512];
      gvb[r] = *(const uint2*)&gx[gbase[r] + (size_t)t1*512];
    }
  }
  __syncthreads();

#define STEP(IT, P, GV) { \
    const int t_ = d ? (T-1-(IT)) : (IT); \
    i32x4 af[4]; \
    _Pragma("unroll") \
    for (int kk=0;kk<4;kk++) \
      af[kk] = *(const i32x4*)&hbuf[(P)^1][l7][(kk*32 + g4*8) ^ sw_rd]; \
    f32x4 acc[4]; \
    _Pragma("unroll") \
    for (int r=0;r<4;r++){ \
      uint32_t lo = GV[r].x, hi = GV[r].y; \
      acc[0][r] = __uint_as_float(lo << 16); \
      acc[1][r] = __uint_as_float(lo & 0xffff0000u); \
      acc[2][r] = __uint_as_float(hi << 16); \
      acc[3][r] = __uint_as_float(hi & 0xffff0000u); \
    } \
    if ((IT) + 2 < T){ \
      const int tn_ = d ? (T-3-(IT)) : ((IT)+2); \
      _Pragma("unroll") \
      for (int r=0;r<4;r++) \
        GV[r] = *(const uint2*)&gx[gbase[r] + (size_t)tn_*512]; \
    } \
    _Pragma("unroll") \
    for (int kk=0;kk<4;kk++) \
      _Pragma("unroll") \
      for (int g=0; g<4; g++) \
        acc[g] = mfma16(af[kk], bw[g][kk], acc[g]); \
    asm volatile("s_nop 7\ns_nop 7\ns_nop 7\ns_nop 7":::); \
    const bool interior_ = (t_ >= 1) && (t_ <= T-2); \
    _Pragma("unroll") \
    for (int r=0;r<4;r++){ \
      float iv = sigm(acc[0][r]); \
      float fv = sigm(acc[1][r]); \
      float gg = tanhf_(acc[2][r]); \
      float ov = sigm(acc[3][r]); \
      c4[r] = fv*c4[r] + iv*gg; \
      float hv = ov * tanhf_(c4[r]); \
      u16 hb = f2bf(hv); \
      if (realln){ \
        const int row_ = row4 + r; \
        hbuf[P][row_][gcol ^ (row_ << 3)] = hb; \
        if (interior_) outp[ob[r] + (size_t)(t_-1)*SQ] = hb; \
      } \
    } \
    asm volatile("s_waitcnt lgkmcnt(0)" ::: "memory"); \
    __builtin_amdgcn_s_barrier(); \
    asm volatile("" ::: "memory"); \
  }

  for (int it = 0; it < T; it += 2){   // T is even (82 or 62)
    STEP(it, 0, gva)
    STEP(it+1, 1, gvb)
  }
#undef STEP
}

// ---------------- head/tail ----------------

__global__ void k_conv(const u16* __restrict__ o5, const float* __restrict__ cw,
                       const float* __restrict__ cb, float* __restrict__ z){
  int out = blockIdx.x*4 + (threadIdx.x>>6);
  int lane = threadIdx.x & 63;
  const u16* src = o5 + (size_t)out*256 + lane*4;
  uint2 v = *(const uint2*)src;
  float4 wv = *(const float4*)(cw + lane*4);
  float s = bf2f((u16)(v.x & 0xffffu))*wv.x + bf2f((u16)(v.x >> 16))*wv.y
          + bf2f((u16)(v.y & 0xffffu))*wv.z + bf2f((u16)(v.y >> 16))*wv.w;
  for (int o=32;o;o>>=1) s += __shfl_down(s, o);
  if (lane == 0) z[out] = s + cb[0];
}

// bilinear(align_corners) + exp at pixel (y,x) of plane z[n]
__device__ __forceinline__ float bil_exp(const float* __restrict__ zp_n, int pix){
  int y = pix / 640, x = pix - (pix/640)*640;
  float py = y * (59.0f/479.0f); int y0 = (int)py; if (y0 > 58) y0 = 58; float fy = py - (float)y0;
  float px = x * (79.0f/639.0f); int x0 = (int)px; if (x0 > 78) x0 = 78; float fx = px - (float)x0;
  const float* zp = zp_n + y0*80 + x0;
  float a = zp[0], b = zp[1], c = zp[80], dd = zp[81];
  float col0 = a*(1.0f-fy) + c*fy;
  float col1 = b*(1.0f-fy) + dd*fy;
  float val = col0*(1.0f-fx) + col1*fx;
  return __expf(val);
}

// softmax denominator: grid (75, 8); 16 px/thread; one padded atomic per block
__global__ void k_sum(const float* __restrict__ z, float* __restrict__ sums){
  __shared__ float red[4];
  int n = blockIdx.y;
  const float* zn = z + (size_t)n*4800;
  int base = blockIdx.x*4096 + threadIdx.x;
  float s = 0.0f;
#pragma unroll
  for (int j=0;j<16;j++) s += bil_exp(zn, base + j*256);
  for (int o=32;o;o>>=1) s += __shfl_down(s, o);
  if ((threadIdx.x & 63) == 0) red[threadIdx.x >> 6] = s;
  __syncthreads();
  if (threadIdx.x == 0) atomicAdd(&sums[n*32], red[0]+red[1]+red[2]+red[3]);
}

// normalize: recompute exp(bilinear) (z is L2-resident), divide by sum
__global__ void k_norm(const float* __restrict__ z, const float* __restrict__ sums,
                       float* __restrict__ out){
  int n = blockIdx.y;
  int pix = blockIdx.x*256 + threadIdx.x;
  float e = bil_exp(z + (size_t)n*4800, pix);
  out[(size_t)n*307200 + pix] = e / sums[n*32];
}

// ---------------- launcher ----------------

extern "C" void kernel_launch(void* const* d_in, const int* in_sizes, int n_in,
                              void* d_out, int out_size, void* d_ws, size_t ws_size,
                              hipStream_t stream){
  const float* lf    = (const float*)d_in[0];
  const float* ctx   = (const float*)d_in[1];
  const float* fc1w  = (const float*)d_in[2];
  const float* fc1b  = (const float*)d_in[3];
  const float* fcrw  = (const float*)d_in[4];
  const float* fcrb  = (const float*)d_in[5];
  const float* convw = (const float*)d_in[6];
  const float* convb = (const float*)d_in[7];
  const float *wih[4], *whh[4], *bih[4], *bhh[4];
  for (int p=0;p<4;p++){
    wih[p] = (const float*)d_in[8 + 4*p + 0];
    whh[p] = (const float*)d_in[8 + 4*p + 1];
    bih[p] = (const float*)d_in[8 + 4*p + 2];
    bhh[p] = (const float*)d_in[8 + 4*p + 3];
  }
  uint8_t* ws = (uint8_t*)d_ws;
  u16* wihb0 = (u16*)(ws + 0);          // 2*512*512  bf16 (gate-permuted)
  u16* wihb1 = (u16*)(ws + 1048576);    // 2*512*256
  u16* wihb2 = (u16*)(ws + 1572864);
  u16* wihb3 = (u16*)(ws + 2097152);
  u16* c1b   = (u16*)(ws + 2621440);    // 8*512
  u16* crb   = (u16*)(ws + 2629632);    // 8*256
  float* sums= (float*)(ws + 2633728);  // 8 slots, 128B-padded (1024 B)
  const size_t SEQ = 2641920;
  u16* seq  = (u16*)(ws + SEQ);                       // max 39424*512 bf16 = 40370176 B
  float* z  = (float*)(ws + SEQ);                     // aliased (dead seq), 153600 B
  u16* gx   = (u16*)(ws + SEQ + 40370176);            // 2*39680*512 bf16 = 81264640 B
  u16* o5   = (u16*)(ws + SEQ + 40370176 + 81264640); // 8*4800*256 bf16 = 19660800 B

  hipMemsetAsync(sums, 0, 1024, stream);
  k_f2bf_perm<<<2048,256,0,stream>>>(wih[0], wihb0, 9);
  k_f2bf_perm<<<1024,256,0,stream>>>(wih[1], wihb1, 8);
  k_f2bf_perm<<<1024,256,0,stream>>>(wih[2], wihb2, 8);
  k_f2bf_perm<<<1024,256,0,stream>>>(wih[3], wihb3, 8);
  k_ctx<<<24,256,0,stream>>>(ctx, fc1w, fc1b, fcrw, fcrb, c1b, crb);

  // pass 1 (h1, row):  S=480 T=82 K=512   (308 m-blocks -> 39*64 = 2496 wgs)
  k_ends<<<960,256,0,stream>>>(seq, c1b, 480, 82, 512, 60);
  k_tr<<<dim3(480,16),256,0,stream>>>(lf, seq);
  k_gemm<<<2496,256,0,stream>>>(seq, wihb0, bih[0], bhh[0], gx, 39424, 512, 308);
  k_ends<<<640,256,0,stream>>>(seq, crb, 640, 62, 256, 80);     // v1 ends
  k_scan<<<dim3(60,2),512,0,stream>>>(gx, whh[0], seq, 480, 82, 60, 39424,
                                      80*62*256, 256, 62*256, 256);
  // pass 2 (v1, col):  S=640 T=62 K=256   (310 m-blocks -> 39*64 = 2496 wgs)
  k_gemm<<<2496,256,0,stream>>>(seq, wihb1, bih[1], bhh[1], gx, 39680, 256, 310);
  k_ends<<<480,256,0,stream>>>(seq, crb, 480, 82, 256, 60);     // h2 ends
  k_scan<<<dim3(80,2),512,0,stream>>>(gx, whh[1], seq, 640, 62, 80, 39680,
                                      60*82*256, 256, 82*256, 256);
  // pass 3 (h2, row):  S=480 T=82 K=256
  k_gemm<<<2496,256,0,stream>>>(seq, wihb2, bih[2], bhh[2], gx, 39424, 256, 308);
  k_ends<<<640,256,0,stream>>>(seq, crb, 640, 62, 256, 80);     // v2 ends
  k_scan<<<dim3(60,2),512,0,stream>>>(gx, whh[2], seq, 480, 82, 60, 39424,
                                      80*62*256, 256, 62*256, 256);
  // pass 4 (v2, col):  S=640 T=62 K=256
  k_gemm<<<2496,256,0,stream>>>(seq, wihb3, bih[3], bhh[3], gx, 39680, 256, 310);
  k_scan<<<dim3(80,2),512,0,stream>>>(gx, whh[3], o5, 640, 62, 80, 39680,
                                      60*80*256, 256, 80*256, 0);
  // head
  k_conv<<<9600,256,0,stream>>>(o5, convw, convb, z);
  k_sum<<<dim3(75,8),256,0,stream>>>(z, sums);
  k_norm<<<dim3(1200,8),256,0,stream>>>(z, sums, (float*)d_out);
}

// Round 10
// 695.122 us; speedup vs baseline: 1.1246x; 1.1246x over previous
//
#include <hip/hip_runtime.h>
#include <stdint.h>

typedef unsigned short u16;
typedef float f32x4 __attribute__((ext_vector_type(4)));
typedef int   i32x4 __attribute__((ext_vector_type(4)));

__device__ __forceinline__ u16 f2bf(float f){
  union { float f; uint32_t u; } v; v.f = f;
  uint32_t r = v.u + 0x7FFFu + ((v.u >> 16) & 1u);
  return (u16)(r >> 16);
}
__device__ __forceinline__ float bf2f(u16 b){
  union { uint32_t u; float f; } v; v.u = ((uint32_t)b) << 16; return v.f;
}
// fast sigmoid / tanh: v_exp + v_rcp (no full-precision div)
__device__ __forceinline__ float sigm(float x){
  return __builtin_amdgcn_rcpf(1.0f + __expf(-x));
}
__device__ __forceinline__ float tanhf_(float x){
  float t = __builtin_amdgcn_rcpf(__expf(2.0f*x) + 1.0f);
  return 1.0f - 2.0f*t;
}
__device__ __forceinline__ f32x4 mfma16(i32x4 a, i32x4 b, f32x4 c){
  asm("v_mfma_f32_16x16x32_bf16 %0, %1, %2, %0" : "+v"(c) : "v"(a), "v"(b));
  return c;
}
__device__ __forceinline__ void stage16(u16* lds_wave_base, const u16* g){
  uint32_t* l32 = (uint32_t*)lds_wave_base;
  __builtin_amdgcn_global_load_lds((const __attribute__((address_space(1))) uint32_t*)g,
                                   (__attribute__((address_space(3))) uint32_t*)l32,
                                   16, 0, 0);
}

// ---------------- small utility kernels ----------------

// wih f32 -> bf16 with gate-interleave permutation folded in:
// dst[d][p][k] = src[d][(p&3)*128 + (p>>2)][k]   (p in [0,512), k in [0,K))
__global__ void k_f2bf_perm(const float* __restrict__ src, u16* __restrict__ dst, int Klog){
  int i = blockIdx.x*256 + threadIdx.x;     // exactly 2*512*K threads launched
  int K = 1 << Klog;
  int k = i & (K-1);
  int p = (i >> Klog) & 511;
  int d = i >> (Klog + 9);
  int orig = ((p & 3) << 7) | (p >> 2);
  dst[i] = f2bf(src[(((size_t)d*512 + orig) << Klog) + k]);
}

__global__ void k_ctx(const float* __restrict__ ctx,
                      const float* __restrict__ fc1w, const float* __restrict__ fc1b,
                      const float* __restrict__ fcrw, const float* __restrict__ fcrb,
                      u16* __restrict__ c1b, u16* __restrict__ crb){
  int idx = blockIdx.x*256 + threadIdx.x;
  if (idx < 4096){
    int n = idx >> 9, j = idx & 511;
    const float* c = ctx + n*128; const float* w = fc1w + j*128;
    float s = fc1b[j];
    for (int k=0;k<128;k++) s += c[k]*w[k];
    c1b[idx] = f2bf(s);
  } else if (idx < 6144){
    int t = idx - 4096; int n = t >> 8, j = t & 255;
    const float* c = ctx + n*128; const float* w = fcrw + j*128;
    float s = fcrb[j];
    for (int k=0;k<128;k++) s += c[k]*w[k];
    crb[t] = f2bf(s);
  }
}

__global__ void k_ends(u16* __restrict__ seq, const u16* __restrict__ ctxb,
                       int S, int T, int D, int P1){
  int idx = blockIdx.x*256 + threadIdx.x;
  if (idx >= S*D) return;
  int s = idx / D, c = idx % D;
  int n = s / P1;
  u16 v = ctxb[n*D + c];
  size_t base = (size_t)s * T * D;
  seq[base + c] = v;
  seq[base + (size_t)(T-1)*D + c] = v;
}

__global__ void k_tr(const float* __restrict__ lf, u16* __restrict__ seq){
  __shared__ float tile[32][81];
  int s = blockIdx.x;            // n*60+h
  int n = s / 60;
  int h = s - n*60;
  int c0 = blockIdx.y * 32;
  const float* src = lf + ((size_t)(n*512 + c0)*60 + h)*80;
  for (int i = 0; i < 10; i++){
    int idx = i*256 + threadIdx.x;   // 2560 = 32c*80w
    int w = idx % 80, ci = idx / 80;
    tile[ci][w] = src[(size_t)ci*4800 + w];
  }
  __syncthreads();
  u16* dst = seq + (size_t)s*82*512 + c0;
  for (int i = 0; i < 10; i++){
    int idx = i*256 + threadIdx.x;
    int ci = idx % 32, w = idx / 32;
    dst[(size_t)(w+1)*512 + ci] = f2bf(tile[ci][w]);
  }
}

// ---------------- GEMM: gx[m][p] = seq[m][:] @ wperm[p][:] + bias[perm(p)] ----------------
// r9 structure kept (dbuf stage-early; XCD-aware wgid mapping).
__launch_bounds__(256)
__global__ void k_gemm(const u16* __restrict__ A, const u16* __restrict__ Bw,
                       const float* __restrict__ bih, const float* __restrict__ bhh,
                       u16* __restrict__ gx, int Mpad, int K, int Mb){
  const int wg = blockIdx.x;
  const int q = wg >> 6, rem = wg & 63;
  const int j = rem >> 3, r8 = rem & 7;
  const int m = q*8 + r8;
  if (m >= Mb) return;
  const int m0 = m * 128;
  const int n0 = (j & 3) * 128;
  const int d = j >> 2;

  __shared__ __align__(16) u16 As[2][4096];
  __shared__ __align__(16) u16 Bs[2][4096];
  const int tid = threadIdx.x;
  const u16* Bd = Bw + (size_t)d * 512 * K;
  const int lane = tid & 63, wid = tid >> 6;
  const int wy = wid >> 1, wx = wid & 1;
  const int l15 = lane & 15, g4 = lane >> 4;
  const int lr = lane & 15;     // staged row within 16-row region
  const int lg = lane >> 4;     // staged k-granule (8 u16 = 16B)

  f32x4 acc[4][4];
#pragma unroll
  for (int i=0;i<4;i++)
#pragma unroll
    for (int jj=0;jj<4;jj++) acc[i][jj] = 0.0f;

  const size_t arow_lo = (size_t)(m0 + wid*16      + lr)*K + lg*8;
  const size_t arow_hi = (size_t)(m0 + 64 + wid*16 + lr)*K + lg*8;
  const size_t brow_lo = (size_t)(n0 + wid*16      + lr)*K + lg*8;
  const size_t brow_hi = (size_t)(n0 + 64 + wid*16 + lr)*K + lg*8;

#define STAGE(B, K0) { \
    stage16(&As[B][wid*512],        A  + arow_lo + (K0)); \
    stage16(&As[B][wid*512 + 2048], A  + arow_hi + (K0)); \
    stage16(&Bs[B][wid*512],        Bd + brow_lo + (K0)); \
    stage16(&Bs[B][wid*512 + 2048], Bd + brow_hi + (K0)); \
  }

  STAGE(0, 0)
  __syncthreads();                 // drains vmcnt: buf0 ready

  int cur = 0;
  for (int k0 = 0; k0 < K; k0 += 32){
    const bool more = (k0 + 32 < K);
    if (more) STAGE(cur^1, k0+32)  // issue next-round staging early
    i32x4 af[4], bfr[4];
#pragma unroll
    for (int i=0;i<4;i++){
      af[i]  = *(const i32x4*)&As[cur][wy*2048 + i*512 + lane*8];
      bfr[i] = *(const i32x4*)&Bs[cur][wx*2048 + i*512 + lane*8];
    }
#pragma unroll
    for (int i=0;i<4;i++)
#pragma unroll
      for (int jj=0;jj<4;jj++)
        acc[i][jj] = mfma16(af[i], bfr[jj], acc[i][jj]);
    if (more){
      __syncthreads();             // drains staging; all waves done reading cur
      cur ^= 1;
    }
  }
#undef STAGE

  asm volatile("s_nop 7\ns_nop 7\ns_nop 7\ns_nop 7":::);
#pragma unroll
  for (int jj=0;jj<4;jj++){
    int col = n0 + wx*64 + jj*16 + l15;
    int orig = ((col & 3) << 7) | (col >> 2);
    float bs = bih[d*512 + orig] + bhh[d*512 + orig];
#pragma unroll
    for (int i=0;i<4;i++){
      int row = m0 + wy*64 + i*16 + g4*4;
      size_t base = ((size_t)d*Mpad + row)*512 + col;
#pragma unroll
      for (int r=0;r<4;r++)
        gx[base + (size_t)r*512] = f2bf(acc[i][jj][r] + bs);
    }
  }
}

// ---------------- LSTM scan: 1 WG = 4 sequences x 1 direction ----------------
// r10: ownership split. MFMA D-quadrants duplicate the 4 seqs 4x (hbuf row =
// l15&3); every lane's reg r holds seq s0+r, so lane g4 OWNS reg g4 = seq
// s0+g4. Per lane per step: 1 gx uint2 load, 1 gate-math block, 1 LDS write,
// 1 store (was 4x each with half the lanes' results discarded). Grid 240/320
// WGs -> all CUs busy. Bit-exact: mirror MFMA rows consume identical A inputs,
// gate expressions unchanged.
__launch_bounds__(512, 2)
__global__ void k_scan(const u16* __restrict__ gx, const float* __restrict__ whh,
                       u16* __restrict__ outp, int S, int T, int P1, int Mpad,
                       int SN, int SP, int SQ, int OFF){
  __shared__ __align__(16) u16 hbuf[2][4][128];
  const int tid = threadIdx.x;
  const int lane = tid & 63, w = tid >> 6;
  const int l15 = lane & 15, g4 = lane >> 4;
  const int d = blockIdx.y;
  const int s0 = blockIdx.x * 4;
  const int gcol = w*16 + l15;
  const int l3 = l15 & 3;
  const int sw_rd = l3 << 3;
  const int swg = g4 << 3;
  const bool odd = (g4 & 1) != 0;
  const bool hi2 = g4 >= 2;

  for (int i = tid; i < 2*4*128; i += 512) ((u16*)hbuf)[i] = 0;

  // B fragments: whh[d][g*128+gcol][k], k = kk*32 + g4*8 + j (same bijection as A side)
  i32x4 bw[4][4];
  {
    const float* wb = whh + (size_t)d*512*128;
#pragma unroll
    for (int g=0; g<4; g++){
      const float* wr = wb + (size_t)(g*128 + gcol)*128 + g4*8;
#pragma unroll
      for (int kk=0; kk<4; kk++){
        f32x4 lo = *(const f32x4*)(wr + kk*32);
        f32x4 hi = *(const f32x4*)(wr + kk*32 + 4);
        union { u16 h[8]; i32x4 v; } u;
#pragma unroll
        for (int j=0;j<4;j++){ u.h[j] = f2bf(lo[j]); u.h[4+j] = f2bf(hi[j]); }
        bw[g][kk] = u.v;
      }
    }
  }

  // own sequence: s0 + g4
  size_t gbase, ob;
  {
    int s = s0 + g4;
    gbase = ((size_t)d*Mpad + (size_t)s*T)*512 + gcol*4;
    int n = s / P1, p = s - n*P1;
    ob = (size_t)n*SN + (size_t)p*SP + OFF + d*128 + gcol;
  }

  float c1 = 0.0f;
  uint2 gva, gvb;
  {
    int t0 = d ? (T-1) : 0;
    int t1 = d ? (T-2) : 1;
    gva = *(const uint2*)&gx[gbase + (size_t)t0*512];
    gvb = *(const uint2*)&gx[gbase + (size_t)t1*512];
  }
  __syncthreads();

#define STEP(IT, P, GV) { \
    const int t_ = d ? (T-1-(IT)) : (IT); \
    i32x4 af[4]; \
    _Pragma("unroll") \
    for (int kk=0;kk<4;kk++) \
      af[kk] = *(const i32x4*)&hbuf[(P)^1][l3][(kk*32 + g4*8) ^ sw_rd]; \
    float vi = __uint_as_float(GV.x << 16); \
    float vf = __uint_as_float(GV.x & 0xffff0000u); \
    float vg = __uint_as_float(GV.y << 16); \
    float vo = __uint_as_float(GV.y & 0xffff0000u); \
    f32x4 acc[4]; \
    acc[0] = (f32x4){vi,vi,vi,vi}; \
    acc[1] = (f32x4){vf,vf,vf,vf}; \
    acc[2] = (f32x4){vg,vg,vg,vg}; \
    acc[3] = (f32x4){vo,vo,vo,vo}; \
    if ((IT) + 2 < T){ \
      const int tn_ = d ? (T-3-(IT)) : ((IT)+2); \
      GV = *(const uint2*)&gx[gbase + (size_t)tn_*512]; \
    } \
    _Pragma("unroll") \
    for (int kk=0;kk<4;kk++) \
      _Pragma("unroll") \
      for (int g=0; g<4; g++) \
        acc[g] = mfma16(af[kk], bw[g][kk], acc[g]); \
    asm volatile("s_nop 7\ns_nop 7\ns_nop 7\ns_nop 7":::); \
    float x0a = odd ? acc[0][1] : acc[0][0]; \
    float x0b = odd ? acc[0][3] : acc[0][2]; \
    float xi  = hi2 ? x0b : x0a; \
    float x1a = odd ? acc[1][1] : acc[1][0]; \
    float x1b = odd ? acc[1][3] : acc[1][2]; \
    float xf  = hi2 ? x1b : x1a; \
    float x2a = odd ? acc[2][1] : acc[2][0]; \
    float x2b = odd ? acc[2][3] : acc[2][2]; \
    float xg  = hi2 ? x2b : x2a; \
    float x3a = odd ? acc[3][1] : acc[3][0]; \
    float x3b = odd ? acc[3][3] : acc[3][2]; \
    float xo  = hi2 ? x3b : x3a; \
    float iv = sigm(xi); \
    float fv = sigm(xf); \
    float gg = tanhf_(xg); \
    float ov = sigm(xo); \
    c1 = fv*c1 + iv*gg; \
    float hv = ov * tanhf_(c1); \
    u16 hb = f2bf(hv); \
    hbuf[P][g4][gcol ^ swg] = hb; \
    if ((t_ >= 1) && (t_ <= T-2)) outp[ob + (size_t)(t_-1)*SQ] = hb; \
    asm volatile("s_waitcnt lgkmcnt(0)" ::: "memory"); \
    __builtin_amdgcn_s_barrier(); \
    asm volatile("" ::: "memory"); \
  }

  for (int it = 0; it < T; it += 2){   // T is even (82 or 62)
    STEP(it, 0, gva)
    STEP(it+1, 1, gvb)
  }
#undef STEP
}

// ---------------- head/tail ----------------

__global__ void k_conv(const u16* __restrict__ o5, const float* __restrict__ cw,
                       const float* __restrict__ cb, float* __restrict__ z){
  int out = blockIdx.x*4 + (threadIdx.x>>6);
  int lane = threadIdx.x & 63;
  const u16* src = o5 + (size_t)out*256 + lane*4;
  uint2 v = *(const uint2*)src;
  float4 wv = *(const float4*)(cw + lane*4);
  float s = bf2f((u16)(v.x & 0xffffu))*wv.x + bf2f((u16)(v.x >> 16))*wv.y
          + bf2f((u16)(v.y & 0xffffu))*wv.z + bf2f((u16)(v.y >> 16))*wv.w;
  for (int o=32;o;o>>=1) s += __shfl_down(s, o);
  if (lane == 0) z[out] = s + cb[0];
}

// bilinear(align_corners) + exp at pixel (y,x) of plane z[n]
__device__ __forceinline__ float bil_exp(const float* __restrict__ zp_n, int pix){
  int y = pix / 640, x = pix - (pix/640)*640;
  float py = y * (59.0f/479.0f); int y0 = (int)py; if (y0 > 58) y0 = 58; float fy = py - (float)y0;
  float px = x * (79.0f/639.0f); int x0 = (int)px; if (x0 > 78) x0 = 78; float fx = px - (float)x0;
  const float* zp = zp_n + y0*80 + x0;
  float a = zp[0], b = zp[1], c = zp[80], dd = zp[81];
  float col0 = a*(1.0f-fy) + c*fy;
  float col1 = b*(1.0f-fy) + dd*fy;
  float val = col0*(1.0f-fx) + col1*fx;
  return __expf(val);
}

// softmax denominator: grid (75, 8); 16 px/thread; one padded atomic per block
__global__ void k_sum(const float* __restrict__ z, float* __restrict__ sums){
  __shared__ float red[4];
  int n = blockIdx.y;
  const float* zn = z + (size_t)n*4800;
  int base = blockIdx.x*4096 + threadIdx.x;
  float s = 0.0f;
#pragma unroll
  for (int j=0;j<16;j++) s += bil_exp(zn, base + j*256);
  for (int o=32;o;o>>=1) s += __shfl_down(s, o);
  if ((threadIdx.x & 63) == 0) red[threadIdx.x >> 6] = s;
  __syncthreads();
  if (threadIdx.x == 0) atomicAdd(&sums[n*32], red[0]+red[1]+red[2]+red[3]);
}

// normalize: recompute exp(bilinear) (z is L2-resident), divide by sum
__global__ void k_norm(const float* __restrict__ z, const float* __restrict__ sums,
                       float* __restrict__ out){
  int n = blockIdx.y;
  int pix = blockIdx.x*256 + threadIdx.x;
  float e = bil_exp(z + (size_t)n*4800, pix);
  out[(size_t)n*307200 + pix] = e / sums[n*32];
}

// ---------------- launcher ----------------

extern "C" void kernel_launch(void* const* d_in, const int* in_sizes, int n_in,
                              void* d_out, int out_size, void* d_ws, size_t ws_size,
                              hipStream_t stream){
  const float* lf    = (const float*)d_in[0];
  const float* ctx   = (const float*)d_in[1];
  const float* fc1w  = (const float*)d_in[2];
  const float* fc1b  = (const float*)d_in[3];
  const float* fcrw  = (const float*)d_in[4];
  const float* fcrb  = (const float*)d_in[5];
  const float* convw = (const float*)d_in[6];
  const float* convb = (const float*)d_in[7];
  const float *wih[4], *whh[4], *bih[4], *bhh[4];
  for (int p=0;p<4;p++){
    wih[p] = (const float*)d_in[8 + 4*p + 0];
    whh[p] = (const float*)d_in[8 + 4*p + 1];
    bih[p] = (const float*)d_in[8 + 4*p + 2];
    bhh[p] = (const float*)d_in[8 + 4*p + 3];
  }
  uint8_t* ws = (uint8_t*)d_ws;
  u16* wihb0 = (u16*)(ws + 0);          // 2*512*512  bf16 (gate-permuted)
  u16* wihb1 = (u16*)(ws + 1048576);    // 2*512*256
  u16* wihb2 = (u16*)(ws + 1572864);
  u16* wihb3 = (u16*)(ws + 2097152);
  u16* c1b   = (u16*)(ws + 2621440);    // 8*512
  u16* crb   = (u16*)(ws + 2629632);    // 8*256
  float* sums= (float*)(ws + 2633728);  // 8 slots, 128B-padded (1024 B)
  const size_t SEQ = 2641920;
  u16* seq  = (u16*)(ws + SEQ);                       // max 39424*512 bf16 = 40370176 B
  float* z  = (float*)(ws + SEQ);                     // aliased (dead seq), 153600 B
  u16* gx   = (u16*)(ws + SEQ + 40370176);            // 2*39680*512 bf16 = 81264640 B
  u16* o5   = (u16*)(ws + SEQ + 40370176 + 81264640); // 8*4800*256 bf16 = 19660800 B

  hipMemsetAsync(sums, 0, 1024, stream);
  k_f2bf_perm<<<2048,256,0,stream>>>(wih[0], wihb0, 9);
  k_f2bf_perm<<<1024,256,0,stream>>>(wih[1], wihb1, 8);
  k_f2bf_perm<<<1024,256,0,stream>>>(wih[2], wihb2, 8);
  k_f2bf_perm<<<1024,256,0,stream>>>(wih[3], wihb3, 8);
  k_ctx<<<24,256,0,stream>>>(ctx, fc1w, fc1b, fcrw, fcrb, c1b, crb);

  // pass 1 (h1, row):  S=480 T=82 K=512   (308 m-blocks -> 39*64 = 2496 wgs)
  k_ends<<<960,256,0,stream>>>(seq, c1b, 480, 82, 512, 60);
  k_tr<<<dim3(480,16),256,0,stream>>>(lf, seq);
  k_gemm<<<2496,256,0,stream>>>(seq, wihb0, bih[0], bhh[0], gx, 39424, 512, 308);
  k_ends<<<640,256,0,stream>>>(seq, crb, 640, 62, 256, 80);     // v1 ends
  k_scan<<<dim3(120,2),512,0,stream>>>(gx, whh[0], seq, 480, 82, 60, 39424,
                                       80*62*256, 256, 62*256, 256);
  // pass 2 (v1, col):  S=640 T=62 K=256   (310 m-blocks -> 39*64 = 2496 wgs)
  k_gemm<<<2496,256,0,stream>>>(seq, wihb1, bih[1], bhh[1], gx, 39680, 256, 310);
  k_ends<<<480,256,0,stream>>>(seq, crb, 480, 82, 256, 60);     // h2 ends
  k_scan<<<dim3(160,2),512,0,stream>>>(gx, whh[1], seq, 640, 62, 80, 39680,
                                       60*82*256, 256, 82*256, 256);
  // pass 3 (h2, row):  S=480 T=82 K=256
  k_gemm<<<2496,256,0,stream>>>(seq, wihb2, bih[2], bhh[2], gx, 39424, 256, 308);
  k_ends<<<640,256,0,stream>>>(seq, crb, 640, 62, 256, 80);     // v2 ends
  k_scan<<<dim3(120,2),512,0,stream>>>(gx, whh[2], seq, 480, 82, 60, 39424,
                                       80*62*256, 256, 62*256, 256);
  // pass 4 (v2, col):  S=640 T=62 K=256
  k_gemm<<<2496,256,0,stream>>>(seq, wihb3, bih[3], bhh[3], gx, 39680, 256, 310);
  k_scan<<<dim3(160,2),512,0,stream>>>(gx, whh[3], o5, 640, 62, 80, 39680,
                                       60*80*256, 256, 80*256, 0);
  // head
  k_conv<<<9600,256,0,stream>>>(o5, convw, convb, z);
  k_sum<<<dim3(75,8),256,0,stream>>>(z, sums);
  k_norm<<<dim3(1200,8),256,0,stream>>>(z, sums, (float*)d_out);
}